// Round 1
// baseline (1197.337 us; speedup 1.0000x reference)
//
#include <hip/hip_runtime.h>
#include <math.h>

typedef unsigned short ushort_t;
typedef __attribute__((ext_vector_type(8))) unsigned short ushortx8;
typedef __attribute__((ext_vector_type(4))) float floatx4;

__device__ __forceinline__ float bf2f(ushort_t u){
  union {unsigned int i; float f;} v; v.i = ((unsigned int)u)<<16; return v.f;
}
__device__ __forceinline__ ushort_t f2bf(float f){
  union {float f; unsigned int i;} v; v.f = f;
  unsigned int x = v.i;
  unsigned int r = x + 0x7fffu + ((x>>16)&1u);
  return (ushort_t)(r>>16);
}

// ---------------- CSR build ----------------
__global__ __launch_bounds__(256) void k_count(const int* __restrict__ col, int* __restrict__ cnt, int E){
  int e = blockIdx.x*256 + threadIdx.x;
  if (e < E) atomicAdd(&cnt[col[e]], 1);
}

__global__ __launch_bounds__(256) void k_scan1(const int* __restrict__ cnt, int* __restrict__ offs,
                                               int* __restrict__ partials, int n){
  __shared__ int buf[256];
  int tid = threadIdx.x;
  int gid = blockIdx.x*256 + tid;
  int v = (gid < n) ? cnt[gid] : 0;
  buf[tid] = v; __syncthreads();
  #pragma unroll
  for (int off=1; off<256; off<<=1){
    int t = (tid >= off) ? buf[tid-off] : 0;
    __syncthreads();
    buf[tid] += t;
    __syncthreads();
  }
  if (gid < n) offs[gid] = buf[tid] - v;      // exclusive within block
  if (tid == 255) partials[blockIdx.x] = buf[255];
}

__global__ __launch_bounds__(256) void k_scan2(int* __restrict__ partials, int nb){
  __shared__ int buf[256];
  int tid = threadIdx.x;
  int v = (tid < nb) ? partials[tid] : 0;
  buf[tid] = v; __syncthreads();
  #pragma unroll
  for (int off=1; off<256; off<<=1){
    int t = (tid >= off) ? buf[tid-off] : 0;
    __syncthreads();
    buf[tid] += t;
    __syncthreads();
  }
  partials[tid] = buf[tid] - v;               // exclusive
}

__global__ __launch_bounds__(256) void k_scan3(int* __restrict__ offs, const int* __restrict__ partials,
                                               int n, int E){
  int gid = blockIdx.x*256 + threadIdx.x;
  if (gid < n) offs[gid] += partials[blockIdx.x];
  if (blockIdx.x == 0 && threadIdx.x == 0) offs[n] = E;
}

__global__ __launch_bounds__(256) void k_fill(const int* __restrict__ col, const int* __restrict__ offs,
                                              int* __restrict__ fill, int* __restrict__ eids, int E){
  int e = blockIdx.x*256 + threadIdx.x;
  if (e >= E) return;
  int c = col[e];
  int pos = offs[c] + atomicAdd(&fill[c], 1);
  eids[pos] = e;
}

// ---------------- GEMM: C[M,NC] = act(A[M,K]@B[K,NC] + bias) (+resid) ----------------
#define TM 64
#define TN 128
#define TK 64

template<bool ABF16, bool OBF16, bool RELU, bool BIAS, bool RESID>
__global__ __launch_bounds__(256) void gemm_kernel(
    const void* __restrict__ Av, const float* __restrict__ B,
    const float* __restrict__ bias, const float* __restrict__ resid,
    void* __restrict__ Cv, int M, int K, int NC)
{
  __shared__ float As[TM][68];        // [row][k], row stride 272B (16B aligned)
  __shared__ float Bs[TK][TN+8];      // [k][col], row stride 544B

  const int tid = threadIdx.x;
  const int bm = blockIdx.y * TM;
  const int n0 = blockIdx.x * TN;
  const int ty = tid >> 4, tx = tid & 15;

  float acc[4][8];
  #pragma unroll
  for (int i=0;i<4;i++)
    #pragma unroll
    for (int j=0;j<8;j++) acc[i][j] = 0.f;

  for (int kc = 0; kc < K; kc += TK){
    // A tile: 64 rows x 64 k
    if (!ABF16){
      const float* A = (const float*)Av;
      #pragma unroll
      for (int q=0;q<4;q++){
        int s = tid + 256*q;
        int row = s >> 4, c4 = s & 15;
        int grow = bm + row; if (grow >= M) grow = M-1;
        floatx4 v = *(const floatx4*)(A + (size_t)grow*K + kc + c4*4);
        *(floatx4*)&As[row][c4*4] = v;
      }
    } else {
      const ushort_t* A = (const ushort_t*)Av;
      #pragma unroll
      for (int q=0;q<2;q++){
        int s = tid + 256*q;
        int row = s >> 3, c8 = s & 7;
        int grow = bm + row; if (grow >= M) grow = M-1;
        ushortx8 v = *(const ushortx8*)(A + (size_t)grow*K + kc + c8*8);
        floatx4 lo, hi;
        #pragma unroll
        for (int j=0;j<4;j++){ lo[j] = bf2f(v[j]); hi[j] = bf2f(v[j+4]); }
        *(floatx4*)&As[row][c8*8]   = lo;
        *(floatx4*)&As[row][c8*8+4] = hi;
      }
    }
    // B tile: 64 k x 128 cols
    #pragma unroll
    for (int q=0;q<8;q++){
      int s = tid + 256*q;
      int kr = s >> 5, c4 = s & 31;
      floatx4 v = *(const floatx4*)(B + (size_t)(kc+kr)*NC + n0 + c4*4);
      *(floatx4*)&Bs[kr][c4*4] = v;
    }
    __syncthreads();

    #pragma unroll 16
    for (int k=0;k<TK;k++){
      float a0 = As[ty*4+0][k], a1 = As[ty*4+1][k], a2 = As[ty*4+2][k], a3 = As[ty*4+3][k];
      const floatx4 b0 = *(const floatx4*)&Bs[k][tx*8];
      const floatx4 b1 = *(const floatx4*)&Bs[k][tx*8+4];
      #pragma unroll
      for (int j=0;j<4;j++){
        float bj = b0[j], bj2 = b1[j];
        acc[0][j]   += a0*bj;  acc[0][j+4] += a0*bj2;
        acc[1][j]   += a1*bj;  acc[1][j+4] += a1*bj2;
        acc[2][j]   += a2*bj;  acc[2][j+4] += a2*bj2;
        acc[3][j]   += a3*bj;  acc[3][j+4] += a3*bj2;
      }
    }
    __syncthreads();
  }

  #pragma unroll
  for (int i=0;i<4;i++){
    int row = bm + ty*4 + i;
    if (row < M){
      #pragma unroll
      for (int j=0;j<8;j++){
        int col = n0 + tx*8 + j;
        float v = acc[i][j];
        if (BIAS) v += bias[col];
        if (RELU) v = v > 0.f ? v : 0.f;
        if (RESID) v += resid[(size_t)row*NC + col];
        if (OBF16) ((ushort_t*)Cv)[(size_t)row*NC + col] = f2bf(v);
        else       ((float*)Cv)[(size_t)row*NC + col] = v;
      }
    }
  }
}

// ---------------- per-node attention logits: s_src/s_dst [N,4] ----------------
__global__ __launch_bounds__(256) void k_sdst(const ushort_t* __restrict__ h,
    const float* __restrict__ a_src, const float* __restrict__ a_dst,
    float* __restrict__ s_src, float* __restrict__ s_dst, int N)
{
  int wid = threadIdx.x >> 6, lane = threadIdx.x & 63;
  int n = blockIdx.x*4 + wid;
  if (n >= N) return;
  int head = lane >> 4;
  int c0 = lane*8;
  int d0 = (lane & 15)*8;
  ushortx8 hv = *(const ushortx8*)(h + (size_t)n*512 + c0);
  float ss = 0.f, sd = 0.f;
  #pragma unroll
  for (int j=0;j<8;j++){
    float f = bf2f(hv[j]);
    ss += f * a_src[head*128 + d0 + j];
    sd += f * a_dst[head*128 + d0 + j];
  }
  #pragma unroll
  for (int m=1;m<16;m<<=1){
    ss += __shfl_xor(ss, m);
    sd += __shfl_xor(sd, m);
  }
  if ((lane & 15) == 0){
    s_src[(size_t)n*4 + head] = ss;
    s_dst[(size_t)n*4 + head] = sd;
  }
}

// ---------------- per-edge exp(leakyrelu(e)) ----------------
__global__ __launch_bounds__(256) void k_eexp(const int* __restrict__ row, const int* __restrict__ col,
    const float* __restrict__ s_src, const float* __restrict__ s_dst,
    float* __restrict__ eexp, int E)
{
  int e = blockIdx.x*256 + threadIdx.x;
  if (e >= E) return;
  int r = row[e], c = col[e];
  floatx4 ss = *(const floatx4*)(s_src + (size_t)r*4);
  floatx4 sd = *(const floatx4*)(s_dst + (size_t)c*4);
  floatx4 o;
  #pragma unroll
  for (int hh=0; hh<4; hh++){
    float v = ss[hh] + sd[hh];
    v = v > 0.f ? v : 0.2f*v;
    o[hh] = expf(v);
  }
  *(floatx4*)(eexp + (size_t)e*4) = o;
}

// ---------------- gather-aggregate: msg[n] = sum_e alpha_e * h[row_e] ----------------
__global__ __launch_bounds__(256) void k_gather(const ushort_t* __restrict__ h,
    const float* __restrict__ eexp, const int* __restrict__ offs,
    const int* __restrict__ eids, const int* __restrict__ row,
    ushort_t* __restrict__ msg, int N)
{
  int wid = threadIdx.x >> 6, lane = threadIdx.x & 63;
  int n = blockIdx.x*4 + wid;
  if (n >= N) return;
  int beg = offs[n], end = offs[n+1];

  // pass 1: denominators (deterministic per node)
  float s0=0.f, s1=0.f, s2=0.f, s3=0.f;
  for (int i = beg + lane; i < end; i += 64){
    int e = eids[i];
    floatx4 ex = *(const floatx4*)(eexp + (size_t)e*4);
    s0 += ex[0]; s1 += ex[1]; s2 += ex[2]; s3 += ex[3];
  }
  #pragma unroll
  for (int m=1;m<64;m<<=1){
    s0 += __shfl_xor(s0, m);
    s1 += __shfl_xor(s1, m);
    s2 += __shfl_xor(s2, m);
    s3 += __shfl_xor(s3, m);
  }
  int head = lane >> 4;
  float denom = (head==0?s0:head==1?s1:head==2?s2:s3) + 1e-8f;
  float invd = 1.0f / denom;

  // pass 2: weighted accumulate, lane owns 8 contiguous channels
  int c0 = lane*8;
  float acc[8];
  #pragma unroll
  for (int j=0;j<8;j++) acc[j] = 0.f;
  for (int i = beg; i < end; i++){
    int e = eids[i];
    int r = row[e];
    float w = eexp[(size_t)e*4 + head] * invd;
    ushortx8 hv = *(const ushortx8*)(h + (size_t)r*512 + c0);
    #pragma unroll
    for (int j=0;j<8;j++) acc[j] += w * bf2f(hv[j]);
  }
  ushortx8 o;
  #pragma unroll
  for (int j=0;j<8;j++) o[j] = f2bf(acc[j]);
  *(ushortx8*)(msg + (size_t)n*512 + c0) = o;
}

// ---------------- column mean over N rows ----------------
__global__ __launch_bounds__(256) void k_colmean(const float* __restrict__ y, float* __restrict__ out, int N){
  __shared__ float buf[256];
  int c = blockIdx.x;
  float s = 0.f;
  for (int r = threadIdx.x; r < N; r += 256) s += y[(size_t)r*128 + c];
  buf[threadIdx.x] = s; __syncthreads();
  for (int off=128; off>0; off>>=1){
    if (threadIdx.x < off) buf[threadIdx.x] += buf[threadIdx.x + off];
    __syncthreads();
  }
  if (threadIdx.x == 0) out[c] = buf[0] / (float)N;
}

extern "C" void kernel_launch(void* const* d_in, const int* in_sizes, int n_in,
                              void* d_out, int out_size, void* d_ws, size_t ws_size,
                              hipStream_t stream)
{
  const int N = in_sizes[0] / 128;
  const int E = in_sizes[1] / 2;

  const float* nodef  = (const float*)d_in[0];
  const int*   row    = (const int*)d_in[1];
  const int*   col    = row + E;
  const float* enc_w1 = (const float*)d_in[2];
  const float* enc_b1 = (const float*)d_in[3];
  const float* enc_w2 = (const float*)d_in[4];
  const float* enc_b2 = (const float*)d_in[5];
  const float* gat_W  = (const float*)d_in[6];
  const float* a_src  = (const float*)d_in[7];
  const float* a_dst  = (const float*)d_in[8];
  const float* out_w  = (const float*)d_in[9];
  const float* out_b  = (const float*)d_in[10];
  const float* w1     = (const float*)d_in[11];
  const float* b1     = (const float*)d_in[12];
  const float* w2     = (const float*)d_in[13];
  const float* b2     = (const float*)d_in[14];

  char* p = (char*)d_ws;
  auto alloc = [&](size_t bytes)->char*{
    char* r = p; p += (bytes + 255) & ~(size_t)255; return r;
  };
  float*    x     = (float*)   alloc((size_t)N*128*4);
  char*     msgb  =            alloc((size_t)N*512*2);   // bf16 [N,512] OR f32 [N,128]
  ushort_t* h     = (ushort_t*)alloc((size_t)N*512*2);
  float*    s_src = (float*)   alloc((size_t)N*4*4);
  float*    s_dst = (float*)   alloc((size_t)N*4*4);
  float*    eexp  = (float*)   alloc((size_t)E*4*4);
  int*      offs  = (int*)     alloc(((size_t)N+1)*4);
  int*      eids  = (int*)     alloc((size_t)E*4);
  int*      cnt   = (int*)     alloc((size_t)N*4);
  int*      fill  = (int*)     alloc((size_t)N*4);
  int*      parts = (int*)     alloc(1024);
  float*    msgF  = (float*)msgb;
  ushort_t* msg   = (ushort_t*)msgb;

  hipMemsetAsync(cnt, 0, (size_t)N*4, stream);
  hipMemsetAsync(fill, 0, (size_t)N*4, stream);

  const int gE = (E + 255)/256;
  const int gN = (N + 255)/256;
  const int gW = (N + 3)/4;       // wave-per-node kernels (4 waves/block)
  const int gy = (N + TM - 1)/TM;
  dim3 blk(256);

  // CSR by destination (built once, reused for all 3 layers)
  k_count<<<gE, blk, 0, stream>>>(col, cnt, E);
  k_scan1<<<gN, blk, 0, stream>>>(cnt, offs, parts, N);
  k_scan2<<<1,  blk, 0, stream>>>(parts, gN);
  k_scan3<<<gN, blk, 0, stream>>>(offs, parts, N, E);
  k_fill <<<gE, blk, 0, stream>>>(col, offs, fill, eids, E);

  // encoder: relu(x@w1+b1)@w2+b2
  gemm_kernel<false,false,true ,true ,false><<<dim3(1,gy), blk, 0, stream>>>(nodef, enc_w1, enc_b1, nullptr, msgF, N, 128, 128);
  gemm_kernel<false,false,false,true ,false><<<dim3(1,gy), blk, 0, stream>>>(msgF,  enc_w2, enc_b2, nullptr, x,    N, 128, 128);

  for (int l = 0; l < 3; l++){
    const float* Wl  = gat_W + (size_t)l*128*512;
    const float* asl = a_src + (size_t)l*512;
    const float* adl = a_dst + (size_t)l*512;
    const float* owl = out_w + (size_t)l*512*128;
    const float* obl = out_b + (size_t)l*128;

    gemm_kernel<false,true ,false,false,false><<<dim3(4,gy), blk, 0, stream>>>(x, Wl, nullptr, nullptr, h, N, 128, 512);
    k_sdst  <<<gW, blk, 0, stream>>>(h, asl, adl, s_src, s_dst, N);
    k_eexp  <<<gE, blk, 0, stream>>>(row, col, s_src, s_dst, eexp, E);
    k_gather<<<gW, blk, 0, stream>>>(h, eexp, offs, eids, row, msg, N);
    gemm_kernel<true ,false,false,true ,true ><<<dim3(1,gy), blk, 0, stream>>>(msg, owl, obl, x, x, N, 512, 128);
  }

  // output MLP -> d_out (f32), then column mean -> d_out + N*128
  gemm_kernel<false,false,true ,true ,false><<<dim3(1,gy), blk, 0, stream>>>(x, w1, b1, nullptr, msgF, N, 128, 128);
  gemm_kernel<false,false,false,true ,false><<<dim3(1,gy), blk, 0, stream>>>(msgF, w2, b2, nullptr, d_out, N, 128, 128);
  k_colmean<<<128, blk, 0, stream>>>((const float*)d_out, (float*)d_out + (size_t)N*128, N);
}

// Round 2
// 726.153 us; speedup vs baseline: 1.6489x; 1.6489x over previous
//
#include <hip/hip_runtime.h>
#include <math.h>

typedef unsigned short ushort_t;
typedef __attribute__((ext_vector_type(8))) unsigned short ushortx8;
typedef __attribute__((ext_vector_type(4))) unsigned short ushortx4;
typedef __attribute__((ext_vector_type(4))) float floatx4;
typedef __attribute__((ext_vector_type(8))) short frag8;   // MFMA A/B operand (8 bf16)

__device__ __forceinline__ float bf2f(ushort_t u){
  union {unsigned int i; float f;} v; v.i = ((unsigned int)u)<<16; return v.f;
}
__device__ __forceinline__ ushort_t f2bf(float f){
  union {float f; unsigned int i;} v; v.f = f;
  unsigned int x = v.i;
  unsigned int r = x + 0x7fffu + ((x>>16)&1u);
  return (ushort_t)(r>>16);
}

__device__ __forceinline__ void gload16(const void* g, void* l){
  __builtin_amdgcn_global_load_lds(
      (const __attribute__((address_space(1))) unsigned int*)g,
      (__attribute__((address_space(3))) unsigned int*)l, 16, 0, 0);
}

// ---------------- CSR build ----------------
__global__ __launch_bounds__(256) void k_count(const int* __restrict__ col, int* __restrict__ cnt, int E){
  int e = blockIdx.x*256 + threadIdx.x;
  if (e < E) atomicAdd(&cnt[col[e]], 1);
}

__global__ __launch_bounds__(256) void k_scan1(const int* __restrict__ cnt, int* __restrict__ offs,
                                               int* __restrict__ partials, int n){
  __shared__ int buf[256];
  int tid = threadIdx.x;
  int gid = blockIdx.x*256 + tid;
  int v = (gid < n) ? cnt[gid] : 0;
  buf[tid] = v; __syncthreads();
  #pragma unroll
  for (int off=1; off<256; off<<=1){
    int t = (tid >= off) ? buf[tid-off] : 0;
    __syncthreads();
    buf[tid] += t;
    __syncthreads();
  }
  if (gid < n) offs[gid] = buf[tid] - v;
  if (tid == 255) partials[blockIdx.x] = buf[255];
}

__global__ __launch_bounds__(256) void k_scan2(int* __restrict__ partials, int nb){
  __shared__ int buf[256];
  int tid = threadIdx.x;
  int v = (tid < nb) ? partials[tid] : 0;
  buf[tid] = v; __syncthreads();
  #pragma unroll
  for (int off=1; off<256; off<<=1){
    int t = (tid >= off) ? buf[tid-off] : 0;
    __syncthreads();
    buf[tid] += t;
    __syncthreads();
  }
  partials[tid] = buf[tid] - v;
}

__global__ __launch_bounds__(256) void k_scan3(int* __restrict__ offs, const int* __restrict__ partials,
                                               int n, int E){
  int gid = blockIdx.x*256 + threadIdx.x;
  if (gid < n) offs[gid] += partials[blockIdx.x];
  if (blockIdx.x == 0 && threadIdx.x == 0) offs[n] = E;
}

__global__ __launch_bounds__(256) void k_fill(const int* __restrict__ col, const int* __restrict__ offs,
                                              int* __restrict__ fill, int* __restrict__ eids, int E){
  int e = blockIdx.x*256 + threadIdx.x;
  if (e >= E) return;
  int c = col[e];
  int pos = offs[c] + atomicAdd(&fill[c], 1);
  eids[pos] = e;
}

// ---------------- conversions ----------------
// f32 -> bf16, 4 elems/thread (n4 = n/4)
__global__ __launch_bounds__(256) void k_conv4(const float* __restrict__ src, ushort_t* __restrict__ dst, int n4){
  int i = blockIdx.x*256 + threadIdx.x;
  if (i >= n4) return;
  floatx4 v = ((const floatx4*)src)[i];
  ushortx4 o;
  #pragma unroll
  for (int j=0;j<4;j++) o[j] = f2bf(v[j]);
  ((ushortx4*)dst)[i] = o;
}

// W[K,NC] f32 -> WT[NC,K] bf16
__global__ __launch_bounds__(256) void k_convT(const float* __restrict__ src, ushort_t* __restrict__ dst,
                                               int K, int NC){
  int idx = blockIdx.x*256 + threadIdx.x;
  if (idx >= K*NC) return;
  int k = idx / NC, n = idx - k*NC;
  dst[(size_t)n*K + k] = f2bf(src[idx]);
}

// ---------------- MFMA GEMM: C[M,NC] = act(A[M,K] @ BT[NC,K]^T + bias) (+resid) ----------------
// A bf16 [M,K] row-major, BT bf16 [NC,K] row-major. K % 64 == 0, NC % 128 == 0.
// OMODE: 0 = f32 only, 1 = bf16 only, 2 = both (f32 Cf + bf16 Cb)
template<bool RELU, bool BIAS, bool RESID, int OMODE>
__global__ __launch_bounds__(256) void mfma_gemm(
    const ushort_t* __restrict__ A, const ushort_t* __restrict__ BT,
    const float* __restrict__ bias, const float* __restrict__ resid,
    float* __restrict__ Cf, ushort_t* __restrict__ Cb,
    int M, int K, int NC)
{
  __shared__ ushort_t As[128*64];
  __shared__ ushort_t Bs[128*64];
  const int tid  = threadIdx.x;
  const int wid  = tid >> 6, lane = tid & 63;
  const int bm   = blockIdx.y * 128, bn = blockIdx.x * 128;
  const int wr   = (wid >> 1) * 64, wc = (wid & 1) * 64;
  const int lm   = lane & 15;
  const int lk   = (lane >> 4) * 8;

  floatx4 acc[4][4];
  #pragma unroll
  for (int i=0;i<4;i++)
    #pragma unroll
    for (int j=0;j<4;j++) acc[i][j] = floatx4{0.f,0.f,0.f,0.f};

  for (int kc = 0; kc < K; kc += 64){
    // stage A-tile [128][64] and B-tile [128][64] (both linear, global_load_lds x16B)
    #pragma unroll
    for (int i = 0; i < 4; i++){
      int chunk = wid*256 + i*64 + lane;   // 16B chunk index, 0..1023
      int r  = chunk >> 3;                 // tile row
      int c8 = chunk & 7;                  // 8-elem column group
      int gr = bm + r; if (gr >= M) gr = M - 1;
      gload16(A  + (size_t)gr*K + kc + c8*8, (char*)As + (size_t)chunk*16);
      gload16(BT + (size_t)(bn + r)*K + kc + c8*8, (char*)Bs + (size_t)chunk*16);
    }
    __syncthreads();

    #pragma unroll
    for (int ks = 0; ks < 2; ks++){
      frag8 a[4], b[4];
      #pragma unroll
      for (int mi=0;mi<4;mi++)
        a[mi] = *(const frag8*)&As[(wr + mi*16 + lm)*64 + ks*32 + lk];
      #pragma unroll
      for (int ni=0;ni<4;ni++)
        b[ni] = *(const frag8*)&Bs[(wc + ni*16 + lm)*64 + ks*32 + lk];
      #pragma unroll
      for (int mi=0;mi<4;mi++)
        #pragma unroll
        for (int ni=0;ni<4;ni++)
          acc[mi][ni] = __builtin_amdgcn_mfma_f32_16x16x32_bf16(a[mi], b[ni], acc[mi][ni], 0, 0, 0);
    }
    __syncthreads();
  }

  // epilogue: C row = (lane>>4)*4 + reg, col = lane&15 within each 16x16 fragment
  const int lr4 = (lane >> 4) * 4;
  #pragma unroll
  for (int mi=0;mi<4;mi++){
    #pragma unroll
    for (int ni=0;ni<4;ni++){
      int colg = bn + wc + ni*16 + lm;
      #pragma unroll
      for (int r=0;r<4;r++){
        int rowg = bm + wr + mi*16 + lr4 + r;
        if (rowg < M){
          float v = acc[mi][ni][r];
          if (BIAS)  v += bias[colg];
          if (RELU)  v = v > 0.f ? v : 0.f;
          if (RESID) v += resid[(size_t)rowg*NC + colg];
          if (OMODE == 0 || OMODE == 2) Cf[(size_t)rowg*NC + colg] = v;
          if (OMODE == 1 || OMODE == 2) Cb[(size_t)rowg*NC + colg] = f2bf(v);
        }
      }
    }
  }
}

// ---------------- per-node attention logits: s_src/s_dst [N,4] ----------------
__global__ __launch_bounds__(256) void k_sdst(const ushort_t* __restrict__ h,
    const float* __restrict__ a_src, const float* __restrict__ a_dst,
    float* __restrict__ s_src, float* __restrict__ s_dst, int N)
{
  int wid = threadIdx.x >> 6, lane = threadIdx.x & 63;
  int n = blockIdx.x*4 + wid;
  if (n >= N) return;
  int head = lane >> 4;
  int c0 = lane*8;
  int d0 = (lane & 15)*8;
  ushortx8 hv = *(const ushortx8*)(h + (size_t)n*512 + c0);
  float ss = 0.f, sd = 0.f;
  #pragma unroll
  for (int j=0;j<8;j++){
    float f = bf2f(hv[j]);
    ss += f * a_src[head*128 + d0 + j];
    sd += f * a_dst[head*128 + d0 + j];
  }
  #pragma unroll
  for (int m=1;m<16;m<<=1){
    ss += __shfl_xor(ss, m);
    sd += __shfl_xor(sd, m);
  }
  if ((lane & 15) == 0){
    s_src[(size_t)n*4 + head] = ss;
    s_dst[(size_t)n*4 + head] = sd;
  }
}

// ---------------- per-edge exp(leakyrelu(e)) ----------------
__global__ __launch_bounds__(256) void k_eexp(const int* __restrict__ row, const int* __restrict__ col,
    const float* __restrict__ s_src, const float* __restrict__ s_dst,
    float* __restrict__ eexp, int E)
{
  int e = blockIdx.x*256 + threadIdx.x;
  if (e >= E) return;
  int r = row[e], c = col[e];
  floatx4 ss = *(const floatx4*)(s_src + (size_t)r*4);
  floatx4 sd = *(const floatx4*)(s_dst + (size_t)c*4);
  floatx4 o;
  #pragma unroll
  for (int hh=0; hh<4; hh++){
    float v = ss[hh] + sd[hh];
    v = v > 0.f ? v : 0.2f*v;
    o[hh] = expf(v);
  }
  *(floatx4*)(eexp + (size_t)e*4) = o;
}

// ---------------- gather-aggregate: msg[n] = sum_e alpha_e * h[row_e] ----------------
__global__ __launch_bounds__(256) void k_gather(const ushort_t* __restrict__ h,
    const float* __restrict__ eexp, const int* __restrict__ offs,
    const int* __restrict__ eids, const int* __restrict__ row,
    ushort_t* __restrict__ msg, int N)
{
  int wid = threadIdx.x >> 6, lane = threadIdx.x & 63;
  int n = blockIdx.x*4 + wid;
  if (n >= N) return;
  int beg = offs[n], end = offs[n+1];

  float s0=0.f, s1=0.f, s2=0.f, s3=0.f;
  for (int i = beg + lane; i < end; i += 64){
    int e = eids[i];
    floatx4 ex = *(const floatx4*)(eexp + (size_t)e*4);
    s0 += ex[0]; s1 += ex[1]; s2 += ex[2]; s3 += ex[3];
  }
  #pragma unroll
  for (int m=1;m<64;m<<=1){
    s0 += __shfl_xor(s0, m);
    s1 += __shfl_xor(s1, m);
    s2 += __shfl_xor(s2, m);
    s3 += __shfl_xor(s3, m);
  }
  int head = lane >> 4;
  float denom = (head==0?s0:head==1?s1:head==2?s2:s3) + 1e-8f;
  float invd = 1.0f / denom;

  int c0 = lane*8;
  float acc[8];
  #pragma unroll
  for (int j=0;j<8;j++) acc[j] = 0.f;
  for (int i = beg; i < end; i++){
    int e = eids[i];
    int r = row[e];
    float w = eexp[(size_t)e*4 + head] * invd;
    ushortx8 hv = *(const ushortx8*)(h + (size_t)r*512 + c0);
    #pragma unroll
    for (int j=0;j<8;j++) acc[j] += w * bf2f(hv[j]);
  }
  ushortx8 o;
  #pragma unroll
  for (int j=0;j<8;j++) o[j] = f2bf(acc[j]);
  *(ushortx8*)(msg + (size_t)n*512 + c0) = o;
}

// ---------------- column mean over N rows ----------------
__global__ __launch_bounds__(256) void k_colmean(const float* __restrict__ y, float* __restrict__ out, int N){
  __shared__ float buf[256];
  int c = blockIdx.x;
  float s = 0.f;
  for (int r = threadIdx.x; r < N; r += 256) s += y[(size_t)r*128 + c];
  buf[threadIdx.x] = s; __syncthreads();
  for (int off=128; off>0; off>>=1){
    if (threadIdx.x < off) buf[threadIdx.x] += buf[threadIdx.x + off];
    __syncthreads();
  }
  if (threadIdx.x == 0) out[c] = buf[0] / (float)N;
}

extern "C" void kernel_launch(void* const* d_in, const int* in_sizes, int n_in,
                              void* d_out, int out_size, void* d_ws, size_t ws_size,
                              hipStream_t stream)
{
  const int N = in_sizes[0] / 128;
  const int E = in_sizes[1] / 2;

  const float* nodef  = (const float*)d_in[0];
  const int*   row    = (const int*)d_in[1];
  const int*   col    = row + E;
  const float* enc_w1 = (const float*)d_in[2];
  const float* enc_b1 = (const float*)d_in[3];
  const float* enc_w2 = (const float*)d_in[4];
  const float* enc_b2 = (const float*)d_in[5];
  const float* gat_W  = (const float*)d_in[6];
  const float* a_src  = (const float*)d_in[7];
  const float* a_dst  = (const float*)d_in[8];
  const float* out_w  = (const float*)d_in[9];
  const float* out_b  = (const float*)d_in[10];
  const float* w1     = (const float*)d_in[11];
  const float* b1     = (const float*)d_in[12];
  const float* w2     = (const float*)d_in[13];
  const float* b2     = (const float*)d_in[14];

  char* p = (char*)d_ws;
  auto alloc = [&](size_t bytes)->char*{
    char* r = p; p += (bytes + 255) & ~(size_t)255; return r;
  };
  float*    x     = (float*)   alloc((size_t)N*128*4);
  char*     msgb  =            alloc((size_t)N*512*2);   // msg bf16 [N,512]; also t1 bf16 [N,128]
  ushort_t* h     = (ushort_t*)alloc((size_t)N*512*2);   // h bf16 [N,512]; also nfb bf16 [N,128] pre-layer-1
  ushort_t* xb    = (ushort_t*)alloc((size_t)N*128*2);   // bf16 shadow of residual x
  float*    s_src = (float*)   alloc((size_t)N*4*4);
  float*    s_dst = (float*)   alloc((size_t)N*4*4);
  float*    eexp  = (float*)   alloc((size_t)E*4*4);
  int*      offs  = (int*)     alloc(((size_t)N+1)*4);
  int*      eids  = (int*)     alloc((size_t)E*4);
  int*      cnt   = (int*)     alloc((size_t)N*4);
  int*      fill  = (int*)     alloc((size_t)N*4);
  int*      parts = (int*)     alloc(1024);
  // bf16 transposed weights
  ushort_t* wt_e1 = (ushort_t*)alloc(16384*2);
  ushort_t* wt_e2 = (ushort_t*)alloc(16384*2);
  ushort_t* wt_W  = (ushort_t*)alloc((size_t)3*65536*2); // [512,128] per layer
  ushort_t* wt_o  = (ushort_t*)alloc((size_t)3*65536*2); // [128,512] per layer
  ushort_t* wt_m1 = (ushort_t*)alloc(16384*2);
  ushort_t* wt_m2 = (ushort_t*)alloc(16384*2);

  ushort_t* nfb = h;                    // node features bf16 (dead after layer-1 W-GEMM)
  ushort_t* t1  = (ushort_t*)msgb;      // MLP intermediate bf16 [N,128]
  ushort_t* msg = (ushort_t*)msgb;

  hipMemsetAsync(cnt, 0, (size_t)N*4, stream);
  hipMemsetAsync(fill, 0, (size_t)N*4, stream);

  const int gE = (E + 255)/256;
  const int gN = (N + 255)/256;
  const int gW = (N + 3)/4;
  const int gy = (N + 127)/128;
  dim3 blk(256);

  // CSR by destination
  k_count<<<gE, blk, 0, stream>>>(col, cnt, E);
  k_scan1<<<gN, blk, 0, stream>>>(cnt, offs, parts, N);
  k_scan2<<<1,  blk, 0, stream>>>(parts, gN);
  k_scan3<<<gN, blk, 0, stream>>>(offs, parts, N, E);
  k_fill <<<gE, blk, 0, stream>>>(col, offs, fill, eids, E);

  // weight conversion (bf16, transposed to [NC,K])
  k_convT<<<(16384+255)/256, blk, 0, stream>>>(enc_w1, wt_e1, 128, 128);
  k_convT<<<(16384+255)/256, blk, 0, stream>>>(enc_w2, wt_e2, 128, 128);
  for (int l=0;l<3;l++){
    k_convT<<<(65536+255)/256, blk, 0, stream>>>(gat_W + (size_t)l*65536, wt_W + (size_t)l*65536, 128, 512);
    k_convT<<<(65536+255)/256, blk, 0, stream>>>(out_w + (size_t)l*65536, wt_o + (size_t)l*65536, 512, 128);
  }
  k_convT<<<(16384+255)/256, blk, 0, stream>>>(w1, wt_m1, 128, 128);
  k_convT<<<(16384+255)/256, blk, 0, stream>>>(w2, wt_m2, 128, 128);

  // node features -> bf16
  k_conv4<<<(N*128/4 + 255)/256, blk, 0, stream>>>(nodef, nfb, N*128/4);

  // encoder: relu(x@w1+b1)@w2+b2 -> x (f32) + xb (bf16)
  mfma_gemm<true ,true ,false,1><<<dim3(1,gy), blk, 0, stream>>>(nfb, wt_e1, enc_b1, nullptr, nullptr, t1, N, 128, 128);
  mfma_gemm<false,true ,false,2><<<dim3(1,gy), blk, 0, stream>>>(t1,  wt_e2, enc_b2, nullptr, x, xb, N, 128, 128);

  for (int l = 0; l < 3; l++){
    const ushort_t* WT  = wt_W + (size_t)l*65536;
    const ushort_t* OT  = wt_o + (size_t)l*65536;
    const float*    asl = a_src + (size_t)l*512;
    const float*    adl = a_dst + (size_t)l*512;
    const float*    obl = out_b + (size_t)l*128;

    mfma_gemm<false,false,false,1><<<dim3(4,gy), blk, 0, stream>>>(xb, WT, nullptr, nullptr, nullptr, h, N, 128, 512);
    k_sdst  <<<gW, blk, 0, stream>>>(h, asl, adl, s_src, s_dst, N);
    k_eexp  <<<gE, blk, 0, stream>>>(row, col, s_src, s_dst, eexp, E);
    k_gather<<<gW, blk, 0, stream>>>(h, eexp, offs, eids, row, msg, N);
    mfma_gemm<false,true ,true ,2><<<dim3(1,gy), blk, 0, stream>>>(msg, OT, obl, x, x, xb, N, 512, 128);
  }

  // output MLP -> d_out (f32), then column mean
  mfma_gemm<true ,true ,false,1><<<dim3(1,gy), blk, 0, stream>>>(xb, wt_m1, b1, nullptr, nullptr, t1, N, 128, 128);
  mfma_gemm<false,true ,false,0><<<dim3(1,gy), blk, 0, stream>>>(t1, wt_m2, b2, nullptr, (float*)d_out, nullptr, N, 128, 128);
  k_colmean<<<128, blk, 0, stream>>>((const float*)d_out, (float*)d_out + (size_t)N*128, N);
}